// Round 1
// baseline (1066.725 us; speedup 1.0000x reference)
//
#include <hip/hip_runtime.h>

typedef _Float16 h8_t __attribute__((ext_vector_type(8)));
typedef _Float16 h4_t __attribute__((ext_vector_type(4)));
typedef float f4_t __attribute__((ext_vector_type(4)));

#define MFMA16(a, b, c) __builtin_amdgcn_mfma_f32_16x16x32_f16((a), (b), (c), 0, 0, 0)

// ---------------------------------------------------------------------------
// f32 -> f16 flat convert (vectorized x4)
__global__ void cvt4(const float* __restrict__ in, _Float16* __restrict__ out, int n4) {
    int i = blockIdx.x * 256 + threadIdx.x;
    if (i < n4) {
        f4_t v = *(const f4_t*)(in + (size_t)i * 4);
        h4_t h;
        for (int j = 0; j < 4; ++j) h[j] = (_Float16)v[j];
        *(h4_t*)(out + (size_t)i * 4) = h;
    }
}

// ---------------------------------------------------------------------------
// W [K=1024][N=1024] f32  ->  Wt [N][K] f16   (tiled transpose)
__global__ void wtrans(const float* __restrict__ W, _Float16* __restrict__ Wt) {
    __shared__ float tile[32][33];
    int tid = threadIdx.x;
    int tx = tid & 31, ty = tid >> 5;
    int nb = blockIdx.x * 32, kb = blockIdx.y * 32;
    for (int p = 0; p < 4; ++p)
        tile[ty + p * 8][tx] = W[(size_t)(kb + ty + p * 8) * 1024 + nb + tx];
    __syncthreads();
    for (int p = 0; p < 4; ++p)
        Wt[(size_t)(nb + ty + p * 8) * 1024 + kb + tx] = (_Float16)tile[tx][ty + p * 8];
}

// ---------------------------------------------------------------------------
// Projection GEMM: Out[m][n] = (sum_k X[m][k]*Wt[n][k] + bias[n]) * scale
// M=8192 (b*1024+s), N=1024 (h*64+d), K=1024.
// vmode==0: Out laid out [b][h][s][64] ; vmode==1: Out [b][h][64][s] (V transposed)
__global__ __launch_bounds__(256, 2) void proj_gemm(
    const _Float16* __restrict__ X, const _Float16* __restrict__ Wt,
    const float* __restrict__ bias, _Float16* __restrict__ Out,
    float scale, int vmode)
{
    __shared__ __align__(16) _Float16 Asm[128][40];
    __shared__ __align__(16) _Float16 Bsm[128][40];
    int tid = threadIdx.x;
    int wave = tid >> 6, lane = tid & 63;
    int l15 = lane & 15, quad = lane >> 4;
    int m0 = blockIdx.x * 128, n0 = blockIdx.y * 128;
    int wm = (wave >> 1) * 64, wn = (wave & 1) * 64;
    f4_t acc[4][4] = {};
    int srow = tid >> 1, skoff = (tid & 1) * 16;

    for (int kt = 0; kt < 1024; kt += 32) {
        h8_t a0 = *(const h8_t*)&X[(size_t)(m0 + srow) * 1024 + kt + skoff];
        h8_t a1 = *(const h8_t*)&X[(size_t)(m0 + srow) * 1024 + kt + skoff + 8];
        h8_t b0 = *(const h8_t*)&Wt[(size_t)(n0 + srow) * 1024 + kt + skoff];
        h8_t b1 = *(const h8_t*)&Wt[(size_t)(n0 + srow) * 1024 + kt + skoff + 8];
        *(h8_t*)&Asm[srow][skoff] = a0;
        *(h8_t*)&Asm[srow][skoff + 8] = a1;
        *(h8_t*)&Bsm[srow][skoff] = b0;
        *(h8_t*)&Bsm[srow][skoff + 8] = b1;
        __syncthreads();
        h8_t af[4], bf[4];
        for (int i = 0; i < 4; ++i) af[i] = *(const h8_t*)&Asm[wm + i * 16 + l15][quad * 8];
        for (int j = 0; j < 4; ++j) bf[j] = *(const h8_t*)&Bsm[wn + j * 16 + l15][quad * 8];
        for (int i = 0; i < 4; ++i)
            for (int j = 0; j < 4; ++j)
                acc[i][j] = MFMA16(af[i], bf[j], acc[i][j]);
        __syncthreads();
    }
    for (int j = 0; j < 4; ++j) {
        int n = n0 + wn + j * 16 + l15;
        float bv = bias[n];
        int h = n >> 6, d = n & 63;
        for (int i = 0; i < 4; ++i) {
            for (int r = 0; r < 4; ++r) {
                int m = m0 + wm + i * 16 + quad * 4 + r;
                int bb = m >> 10, ss = m & 1023;
                float v = (acc[i][j][r] + bv) * scale;
                size_t oidx = vmode ? (((size_t)(bb * 16 + h) * 64 + d) * 1024 + ss)
                                    : (((size_t)(bb * 16 + h) * 1024 + ss) * 64 + d);
                Out[oidx] = (_Float16)v;
            }
        }
    }
}

// ---------------------------------------------------------------------------
// rel B-operand loader: f16 path (pre-converted) or f32 fallback
__device__ inline h8_t ld_rel(const _Float16* relh, const float* relf, size_t idx) {
    if (relh) return *(const h8_t*)(relh + idx);
    f4_t a = *(const f4_t*)(relf + idx);
    f4_t b = *(const f4_t*)(relf + idx + 4);
    h8_t h;
    for (int j = 0; j < 4; ++j) { h[j] = (_Float16)a[j]; h[4 + j] = (_Float16)b[j]; }
    return h;
}

// ---------------------------------------------------------------------------
// Fused attention. WG = (batch b, 16 q-rows) covering all 16 heads.
// Scores computed TRANSPOSED: D[t][q] so softmax rows live in lane dim (l15=q).
// Kh is pre-scaled by 1/8; rel added unscaled (matches reference).
__global__ __launch_bounds__(256, 2) void attn_kernel(
    const _Float16* __restrict__ Qh,   // [B][H][S][64]
    const _Float16* __restrict__ Kh,   // [B][H][S][64], pre-scaled 1/8
    const _Float16* __restrict__ Vt,   // [B][H][64][S]
    const _Float16* __restrict__ relh, // [S][S][64] f16 or nullptr
    const float* __restrict__ relf,    // [S][S][64] f32
    const int* __restrict__ mask,      // [B][S][S] int32 (nonzero = masked)
    float* __restrict__ out)           // [B][S][1024]
{
    __shared__ __align__(16) _Float16 R_lds[16][17][36]; // [q_local][g][t] rel scores f16
    __shared__ __align__(16) _Float16 P_lds[16][16][40]; // [g][q_local][t] probs f16

    const int tid = threadIdx.x;
    const int wave = tid >> 6, lane = tid & 63;
    const int l15 = lane & 15, quad = lane >> 4;
    const int b = blockIdx.y;
    const int q0 = blockIdx.x * 16;

    // persistent B-operand fragments of Q
    h8_t bQ[4][2]; // QK: B[d][q] for wave's 4 heads g
    h8_t bR[4][2]; // rel: B[d][g] for wave's 4 queries q
    for (int gi = 0; gi < 4; ++gi) {
        int g = wave * 4 + gi;
        const _Float16* qp = Qh + ((size_t)(b * 16 + g) * 1024 + q0 + l15) * 64 + quad * 8;
        bQ[gi][0] = *(const h8_t*)qp;
        bQ[gi][1] = *(const h8_t*)(qp + 32);
    }
    for (int qi = 0; qi < 4; ++qi) {
        int q = q0 + wave * 4 + qi;
        const _Float16* qp = Qh + ((size_t)(b * 16 + l15) * 1024 + q) * 64 + quad * 8;
        bR[qi][0] = *(const h8_t*)qp;
        bR[qi][1] = *(const h8_t*)(qp + 32);
    }

    f4_t acc[4][4] = {}; // [gi][dm] O^T frags: rows d, cols q
    float mst[4], lst[4];
    for (int gi = 0; gi < 4; ++gi) { mst[gi] = -1e30f; lst[gi] = 0.0f; }

    for (int t0 = 0; t0 < 1024; t0 += 32) {
        // ---- Phase A: rel GEMMs, D[t][g] per owned q -> R_lds (f16)
        for (int qi = 0; qi < 4; ++qi) {
            int q = q0 + wave * 4 + qi;
            for (int tm = 0; tm < 2; ++tm) {
                f4_t c = {0.f, 0.f, 0.f, 0.f};
                size_t ridx = ((size_t)q * 1024 + t0 + tm * 16 + l15) * 64 + quad * 8;
                c = MFMA16(ld_rel(relh, relf, ridx), bR[qi][0], c);
                c = MFMA16(ld_rel(relh, relf, ridx + 32), bR[qi][1], c);
                h4_t h;
                for (int r = 0; r < 4; ++r) h[r] = (_Float16)c[r];
                *(h4_t*)&R_lds[wave * 4 + qi][l15][tm * 16 + quad * 4] = h;
            }
        }
        __syncthreads();

        // mask bits for this lane's q row (shared across heads)
        int4 mk0 = *(const int4*)&mask[((size_t)b * 1024 + q0 + l15) * 1024 + t0 + quad * 4];
        int4 mk1 = *(const int4*)&mask[((size_t)b * 1024 + q0 + l15) * 1024 + t0 + 16 + quad * 4];
        int mm[8] = {mk0.x, mk0.y, mk0.z, mk0.w, mk1.x, mk1.y, mk1.z, mk1.w};

        // ---- Phase B: QK^T (transposed) + online softmax, all in registers
        for (int gi = 0; gi < 4; ++gi) {
            int g = wave * 4 + gi;
            f4_t s[2];
            for (int tm = 0; tm < 2; ++tm) {
                h4_t rh = *(const h4_t*)&R_lds[l15][g][tm * 16 + quad * 4];
                f4_t c;
                for (int r = 0; r < 4; ++r) c[r] = (float)rh[r];
                const _Float16* kp =
                    Kh + ((size_t)(b * 16 + g) * 1024 + t0 + tm * 16 + l15) * 64 + quad * 8;
                c = MFMA16(*(const h8_t*)kp, bQ[gi][0], c);
                c = MFMA16(*(const h8_t*)(kp + 32), bQ[gi][1], c);
                s[tm] = c;
            }
            for (int tm = 0; tm < 2; ++tm)
                for (int r = 0; r < 4; ++r)
                    if (mm[tm * 4 + r]) s[tm][r] = -1e8f;

            float mx = s[0][0];
            for (int tm = 0; tm < 2; ++tm)
                for (int r = 0; r < 4; ++r) mx = fmaxf(mx, s[tm][r]);
            mx = fmaxf(mx, __shfl_xor(mx, 16));
            mx = fmaxf(mx, __shfl_xor(mx, 32));
            float mnew = fmaxf(mst[gi], mx);
            float alpha = __expf(mst[gi] - mnew);
            mst[gi] = mnew;
            float rs = 0.0f;
            for (int tm = 0; tm < 2; ++tm)
                for (int r = 0; r < 4; ++r) {
                    float p = __expf(s[tm][r] - mnew);
                    s[tm][r] = p;
                    rs += p;
                }
            rs += __shfl_xor(rs, 16);
            rs += __shfl_xor(rs, 32);
            lst[gi] = lst[gi] * alpha + rs;
            for (int dm = 0; dm < 4; ++dm) acc[gi][dm] *= alpha; // alpha uniform per lane (q=l15)
            for (int tm = 0; tm < 2; ++tm) {
                h4_t h;
                for (int r = 0; r < 4; ++r) h[r] = (_Float16)s[tm][r];
                *(h4_t*)&P_lds[g][l15][tm * 16 + quad * 4] = h;
            }
        }
        __syncthreads();

        // ---- Phase C: O^T[d][q] += V^T[d][t] * P^T[t][q]
        for (int gi = 0; gi < 4; ++gi) {
            int g = wave * 4 + gi;
            h8_t bp = *(const h8_t*)&P_lds[g][l15][quad * 8];
            const _Float16* vp = Vt + (size_t)(b * 16 + g) * 64 * 1024 + t0 + quad * 8;
            for (int dm = 0; dm < 4; ++dm) {
                h8_t av = *(const h8_t*)(vp + (size_t)(dm * 16 + l15) * 1024);
                acc[gi][dm] = MFMA16(av, bp, acc[gi][dm]);
            }
        }
        // no barrier needed here: R_lds rewrite is fenced by the Phase-A barrier,
        // P_lds is wave-private (written+read by the g-owning wave only)
    }

    // ---- epilogue: out[b][q][g*64+d] = O^T / l
    for (int gi = 0; gi < 4; ++gi) {
        int g = wave * 4 + gi;
        float linv = 1.0f / lst[gi];
        for (int dm = 0; dm < 4; ++dm) {
            f4_t v = acc[gi][dm] * linv;
            float* op = out + ((size_t)b * 1024 + q0 + l15) * 1024 + g * 64 + dm * 16 + quad * 4;
            *(f4_t*)op = v;
        }
    }
}

// ---------------------------------------------------------------------------
extern "C" void kernel_launch(void* const* d_in, const int* in_sizes, int n_in,
                              void* d_out, int out_size, void* d_ws, size_t ws_size,
                              hipStream_t stream) {
    const float* q    = (const float*)d_in[0];
    const float* k    = (const float*)d_in[1];
    const float* v    = (const float*)d_in[2];
    const float* rel  = (const float*)d_in[3];
    const float* Wq   = (const float*)d_in[4];
    const float* bq   = (const float*)d_in[5];
    const float* Wk   = (const float*)d_in[6];
    const float* bk   = (const float*)d_in[7];
    const float* Wv   = (const float*)d_in[8];
    const float* bv   = (const float*)d_in[9];
    const int*   mask = (const int*)d_in[10];
    float* out = (float*)d_out;

    const size_t NEL = 8ull * 1024 * 1024;      // 8*1024*1024 elements (inputs/projections)
    const size_t WEL = 1024ull * 1024;          // weight elements
    const size_t RELE = 1024ull * 1024 * 64;    // rel elements

    char* w = (char*)d_ws;
    size_t off = 0;
    auto alloc = [&](size_t bytes) { char* p = w + off; off += bytes; return p; };
    _Float16* qx  = (_Float16*)alloc(NEL * 2);
    _Float16* kx  = (_Float16*)alloc(NEL * 2);
    _Float16* vx  = (_Float16*)alloc(NEL * 2);
    _Float16* Wqt = (_Float16*)alloc(WEL * 2);
    _Float16* Wkt = (_Float16*)alloc(WEL * 2);
    _Float16* Wvt = (_Float16*)alloc(WEL * 2);
    _Float16* Qh  = (_Float16*)alloc(NEL * 2);
    _Float16* Kh  = (_Float16*)alloc(NEL * 2);
    _Float16* Vth = (_Float16*)alloc(NEL * 2);
    _Float16* relh = nullptr;
    if (ws_size >= off + RELE * 2) relh = (_Float16*)alloc(RELE * 2);

    // convert inputs to f16
    cvt4<<<(int)(NEL / 4 / 256), 256, 0, stream>>>(q, qx, (int)(NEL / 4));
    cvt4<<<(int)(NEL / 4 / 256), 256, 0, stream>>>(k, kx, (int)(NEL / 4));
    cvt4<<<(int)(NEL / 4 / 256), 256, 0, stream>>>(v, vx, (int)(NEL / 4));
    if (relh)
        cvt4<<<(int)(RELE / 4 / 256), 256, 0, stream>>>(rel, relh, (int)(RELE / 4));

    dim3 tg(32, 32);
    wtrans<<<tg, 256, 0, stream>>>(Wq, Wqt);
    wtrans<<<tg, 256, 0, stream>>>(Wk, Wkt);
    wtrans<<<tg, 256, 0, stream>>>(Wv, Wvt);

    dim3 pg(64, 8);
    proj_gemm<<<pg, 256, 0, stream>>>(qx, Wqt, bq, Qh, 1.0f, 0);
    proj_gemm<<<pg, 256, 0, stream>>>(kx, Wkt, bk, Kh, 0.125f, 0); // fold 1/sqrt(dk)
    proj_gemm<<<pg, 256, 0, stream>>>(vx, Wvt, bv, Vth, 1.0f, 1);  // V transposed

    dim3 ag(64, 8);
    attn_kernel<<<ag, 256, 0, stream>>>(Qh, Kh, Vth, relh, rel, mask, out);
}

// Round 2
// 943.232 us; speedup vs baseline: 1.1309x; 1.1309x over previous
//
#include <hip/hip_runtime.h>

typedef _Float16 h8_t __attribute__((ext_vector_type(8)));
typedef _Float16 h4_t __attribute__((ext_vector_type(4)));
typedef float f4_t __attribute__((ext_vector_type(4)));

#define MFMA16(a, b, c) __builtin_amdgcn_mfma_f32_16x16x32_f16((a), (b), (c), 0, 0, 0)

// async global->LDS DMA, 16B per lane; LDS dest must be wave-uniform base + lane*16
__device__ inline void gl_lds16(const _Float16* g, _Float16* l) {
    __builtin_amdgcn_global_load_lds(
        (const __attribute__((address_space(1))) unsigned int*)g,
        (__attribute__((address_space(3))) unsigned int*)l, 16, 0, 0);
}

// ---------------------------------------------------------------------------
// f32 -> f16 flat convert (vectorized x4)
__global__ void cvt4(const float* __restrict__ in, _Float16* __restrict__ out, int n4) {
    int i = blockIdx.x * 256 + threadIdx.x;
    if (i < n4) {
        f4_t v = *(const f4_t*)(in + (size_t)i * 4);
        h4_t h;
        for (int j = 0; j < 4; ++j) h[j] = (_Float16)v[j];
        *(h4_t*)(out + (size_t)i * 4) = h;
    }
}

// ---------------------------------------------------------------------------
// W [K=1024][N=1024] f32  ->  Wt [N][K] f16   (tiled transpose)
__global__ void wtrans(const float* __restrict__ W, _Float16* __restrict__ Wt) {
    __shared__ float tile[32][33];
    int tid = threadIdx.x;
    int tx = tid & 31, ty = tid >> 5;
    int nb = blockIdx.x * 32, kb = blockIdx.y * 32;
    for (int p = 0; p < 4; ++p)
        tile[ty + p * 8][tx] = W[(size_t)(kb + ty + p * 8) * 1024 + nb + tx];
    __syncthreads();
    for (int p = 0; p < 4; ++p)
        Wt[(size_t)(nb + ty + p * 8) * 1024 + kb + tx] = (_Float16)tile[tx][ty + p * 8];
}

// ---------------------------------------------------------------------------
// Projection GEMM, m97-style: global_load_lds width-16 staging, unpadded
// [128][32] f16 LDS tiles. Out = (X @ Wt^T + bias) * scale.
// vmode==0: Out [b][h][s][64] ; vmode==1: Out [b][h][64][s] (V transposed)
__global__ __launch_bounds__(256, 2) void proj_gemm(
    const _Float16* __restrict__ X, const _Float16* __restrict__ Wt,
    const float* __restrict__ bias, _Float16* __restrict__ Out,
    float scale, int vmode)
{
    __shared__ __align__(16) _Float16 Asm[128 * 32];
    __shared__ __align__(16) _Float16 Bsm[128 * 32];
    int tid = threadIdx.x;
    int wave = tid >> 6, lane = tid & 63;
    int l15 = lane & 15, quad = lane >> 4;
    int m0 = blockIdx.x * 128, n0 = blockIdx.y * 128;
    int wm = (wave >> 1) * 64, wn = (wave & 1) * 64;
    f4_t acc[4][4] = {};
    int f0 = wave * 128 + lane;

    for (int kt = 0; kt < 1024; kt += 32) {
        for (int j = 0; j < 2; ++j) {
            int f = f0 + j * 64;
            int r = f >> 2, c = (f & 3) * 8;
            gl_lds16(&X[(size_t)(m0 + r) * 1024 + kt + c], &Asm[f * 8]);
            gl_lds16(&Wt[(size_t)(n0 + r) * 1024 + kt + c], &Bsm[f * 8]);
        }
        __syncthreads();  // drains vmcnt(0): staged data has landed
        h8_t af[4], bf[4];
        for (int i = 0; i < 4; ++i) af[i] = *(const h8_t*)&Asm[(wm + i * 16 + l15) * 32 + quad * 8];
        for (int j = 0; j < 4; ++j) bf[j] = *(const h8_t*)&Bsm[(wn + j * 16 + l15) * 32 + quad * 8];
        for (int i = 0; i < 4; ++i)
            for (int j = 0; j < 4; ++j)
                acc[i][j] = MFMA16(af[i], bf[j], acc[i][j]);
        __syncthreads();
    }
    for (int j = 0; j < 4; ++j) {
        int n = n0 + wn + j * 16 + l15;
        float bv = bias[n];
        int h = n >> 6, d = n & 63;
        for (int i = 0; i < 4; ++i) {
            for (int r = 0; r < 4; ++r) {
                int m = m0 + wm + i * 16 + quad * 4 + r;
                int bb = m >> 10, ss = m & 1023;
                float v = (acc[i][j][r] + bv) * scale;
                size_t oidx = vmode ? (((size_t)(bb * 16 + h) * 64 + d) * 1024 + ss)
                                    : (((size_t)(bb * 16 + h) * 1024 + ss) * 64 + d);
                Out[oidx] = (_Float16)v;
            }
        }
    }
}

// ---------------------------------------------------------------------------
// rel B-operand loader: f16 path (pre-converted) or f32 fallback
__device__ inline h8_t ld_rel(const _Float16* relh, const float* relf, size_t idx) {
    if (relh) return *(const h8_t*)(relh + idx);
    f4_t a = *(const f4_t*)(relf + idx);
    f4_t b = *(const f4_t*)(relf + idx + 4);
    h8_t h;
    for (int j = 0; j < 4; ++j) { h[j] = (_Float16)a[j]; h[4 + j] = (_Float16)b[j]; }
    return h;
}

// ---------------------------------------------------------------------------
// Fused attention. WG = (batch b, 16 q-rows) covering all 16 heads.
// Scores computed TRANSPOSED: D[t][q] so softmax rows live in lane dim (l15=q).
// Kh pre-scaled by 1/8; rel added unscaled (matches reference).
// This round: batched register loads per phase (one latency exposure each),
// double-buffered R_lds -> ONE barrier per k-tile.
__global__ __launch_bounds__(256, 2) void attn_kernel(
    const _Float16* __restrict__ Qh,   // [B][H][S][64]
    const _Float16* __restrict__ Kh,   // [B][H][S][64], pre-scaled 1/8
    const _Float16* __restrict__ Vt,   // [B][H][64][S]
    const _Float16* __restrict__ relh, // [S][S][64] f16 or nullptr
    const float* __restrict__ relf,    // [S][S][64] f32
    const int* __restrict__ mask,      // [B][S][S] int32 (nonzero = masked)
    float* __restrict__ out)           // [B][S][1024]
{
    __shared__ __align__(16) _Float16 R_lds[2][16][17][36]; // [buf][q_local][g][t]
    __shared__ __align__(16) _Float16 P_lds[16][16][40];    // [g][q_local][t] (wave-private)

    const int tid = threadIdx.x;
    const int wave = tid >> 6, lane = tid & 63;
    const int l15 = lane & 15, quad = lane >> 4;
    const int b = blockIdx.y;
    const int q0 = blockIdx.x * 16;

    // persistent B-operand fragments of Q
    h8_t bQ[4][2]; // QK: B[d][q] for wave's 4 heads g
    h8_t bR[4][2]; // rel: B[d][g] for wave's 4 queries q
    for (int gi = 0; gi < 4; ++gi) {
        int g = wave * 4 + gi;
        const _Float16* qp = Qh + ((size_t)(b * 16 + g) * 1024 + q0 + l15) * 64 + quad * 8;
        bQ[gi][0] = *(const h8_t*)qp;
        bQ[gi][1] = *(const h8_t*)(qp + 32);
    }
    for (int qi = 0; qi < 4; ++qi) {
        int q = q0 + wave * 4 + qi;
        const _Float16* qp = Qh + ((size_t)(b * 16 + l15) * 1024 + q) * 64 + quad * 8;
        bR[qi][0] = *(const h8_t*)qp;
        bR[qi][1] = *(const h8_t*)(qp + 32);
    }

    f4_t acc[4][4] = {}; // [gi][dm] O^T frags: rows d, cols q
    float mst[4], lst[4];
    for (int gi = 0; gi < 4; ++gi) { mst[gi] = -1e30f; lst[gi] = 0.0f; }

    int buf = 0;
    for (int t0 = 0; t0 < 1024; t0 += 32, buf ^= 1) {
        // mask bits for this lane's q row (independent — issue first)
        const int* mrow = &mask[((size_t)b * 1024 + q0 + l15) * 1024 + t0];
        int4 mk0 = *(const int4*)(mrow + quad * 4);
        int4 mk1 = *(const int4*)(mrow + 16 + quad * 4);

        // ---- rel batch: 16 independent loads issued before any consumer
        h8_t relv[4][2][2];
        for (int qi = 0; qi < 4; ++qi) {
            size_t rb = ((size_t)(q0 + wave * 4 + qi) * 1024 + t0 + l15) * 64 + quad * 8;
            relv[qi][0][0] = ld_rel(relh, relf, rb);
            relv[qi][0][1] = ld_rel(relh, relf, rb + 32);
            relv[qi][1][0] = ld_rel(relh, relf, rb + 1024);
            relv[qi][1][1] = ld_rel(relh, relf, rb + 1056);
        }
        // ---- Phase A: rel GEMMs, D[t][g] per owned q -> R_lds[buf]
        for (int qi = 0; qi < 4; ++qi) {
            for (int tm = 0; tm < 2; ++tm) {
                f4_t c = {0.f, 0.f, 0.f, 0.f};
                c = MFMA16(relv[qi][tm][0], bR[qi][0], c);
                c = MFMA16(relv[qi][tm][1], bR[qi][1], c);
                h4_t h;
                for (int r = 0; r < 4; ++r) h[r] = (_Float16)c[r];
                *(h4_t*)&R_lds[buf][wave * 4 + qi][l15][tm * 16 + quad * 4] = h;
            }
        }

        // ---- K batch: issued pre-barrier so latency drains during barrier
        h8_t kv[4][2][2];
        for (int gi = 0; gi < 4; ++gi) {
            const _Float16* kp =
                Kh + ((size_t)(b * 16 + wave * 4 + gi) * 1024 + t0 + l15) * 64 + quad * 8;
            kv[gi][0][0] = *(const h8_t*)kp;
            kv[gi][0][1] = *(const h8_t*)(kp + 32);
            kv[gi][1][0] = *(const h8_t*)(kp + 1024);
            kv[gi][1][1] = *(const h8_t*)(kp + 1056);
        }
        __syncthreads(); // R_lds[buf] visible; also fences R_lds[buf^1] WAR

        int mm[8] = {mk0.x, mk0.y, mk0.z, mk0.w, mk1.x, mk1.y, mk1.z, mk1.w};

        // ---- Phase B: QK^T (transposed) + online softmax, all in registers
        for (int gi = 0; gi < 4; ++gi) {
            int g = wave * 4 + gi;
            f4_t s[2];
            for (int tm = 0; tm < 2; ++tm) {
                h4_t rh = *(const h4_t*)&R_lds[buf][l15][g][tm * 16 + quad * 4];
                f4_t c;
                for (int r = 0; r < 4; ++r) c[r] = (float)rh[r];
                c = MFMA16(kv[gi][tm][0], bQ[gi][0], c);
                c = MFMA16(kv[gi][tm][1], bQ[gi][1], c);
                s[tm] = c;
            }
            for (int tm = 0; tm < 2; ++tm)
                for (int r = 0; r < 4; ++r)
                    if (mm[tm * 4 + r]) s[tm][r] = -1e8f;

            float mx = s[0][0];
            for (int tm = 0; tm < 2; ++tm)
                for (int r = 0; r < 4; ++r) mx = fmaxf(mx, s[tm][r]);
            mx = fmaxf(mx, __shfl_xor(mx, 16));
            mx = fmaxf(mx, __shfl_xor(mx, 32));
            float mnew = fmaxf(mst[gi], mx);
            float alpha = __expf(mst[gi] - mnew);
            mst[gi] = mnew;
            float rs = 0.0f;
            for (int tm = 0; tm < 2; ++tm)
                for (int r = 0; r < 4; ++r) {
                    float p = __expf(s[tm][r] - mnew);
                    s[tm][r] = p;
                    rs += p;
                }
            rs += __shfl_xor(rs, 16);
            rs += __shfl_xor(rs, 32);
            lst[gi] = lst[gi] * alpha + rs;
            for (int dm = 0; dm < 4; ++dm) acc[gi][dm] *= alpha; // alpha uniform per lane (q=l15)
            for (int tm = 0; tm < 2; ++tm) {
                h4_t h;
                for (int r = 0; r < 4; ++r) h[r] = (_Float16)s[tm][r];
                *(h4_t*)&P_lds[g][l15][tm * 16 + quad * 4] = h;
            }
        }

        // ---- V batch (kv regs dead by now)
        h8_t vv[4][4];
        for (int gi = 0; gi < 4; ++gi) {
            const _Float16* vp =
                Vt + (size_t)(b * 16 + wave * 4 + gi) * 65536 + t0 + quad * 8;
            for (int dm = 0; dm < 4; ++dm)
                vv[gi][dm] = *(const h8_t*)(vp + (size_t)(dm * 16 + l15) * 1024);
        }
        // ---- Phase C: O^T[d][q] += V^T[d][t] * P^T[t][q]   (P wave-private)
        for (int gi = 0; gi < 4; ++gi) {
            h8_t bp = *(const h8_t*)&P_lds[wave * 4 + gi][l15][quad * 8];
            for (int dm = 0; dm < 4; ++dm)
                acc[gi][dm] = MFMA16(vv[gi][dm], bp, acc[gi][dm]);
        }
        // no second barrier: R_lds double-buffered, P_lds wave-private
    }

    // ---- epilogue: out[b][q][g*64+d] = O^T / l
    for (int gi = 0; gi < 4; ++gi) {
        int g = wave * 4 + gi;
        float linv = 1.0f / lst[gi];
        for (int dm = 0; dm < 4; ++dm) {
            f4_t v = acc[gi][dm] * linv;
            float* op = out + ((size_t)b * 1024 + q0 + l15) * 1024 + g * 64 + dm * 16 + quad * 4;
            *(f4_t*)op = v;
        }
    }
}

// ---------------------------------------------------------------------------
extern "C" void kernel_launch(void* const* d_in, const int* in_sizes, int n_in,
                              void* d_out, int out_size, void* d_ws, size_t ws_size,
                              hipStream_t stream) {
    const float* q    = (const float*)d_in[0];
    const float* k    = (const float*)d_in[1];
    const float* v    = (const float*)d_in[2];
    const float* rel  = (const float*)d_in[3];
    const float* Wq   = (const float*)d_in[4];
    const float* bq   = (const float*)d_in[5];
    const float* Wk   = (const float*)d_in[6];
    const float* bk   = (const float*)d_in[7];
    const float* Wv   = (const float*)d_in[8];
    const float* bv   = (const float*)d_in[9];
    const int*   mask = (const int*)d_in[10];
    float* out = (float*)d_out;

    const size_t NEL = 8ull * 1024 * 1024;      // activation elements
    const size_t WEL = 1024ull * 1024;          // weight elements
    const size_t RELE = 1024ull * 1024 * 64;    // rel elements

    char* w = (char*)d_ws;
    size_t off = 0;
    auto alloc = [&](size_t bytes) { char* p = w + off; off += bytes; return p; };
    _Float16* qx  = (_Float16*)alloc(NEL * 2);
    _Float16* kx  = (_Float16*)alloc(NEL * 2);
    _Float16* vx  = (_Float16*)alloc(NEL * 2);
    _Float16* Wqt = (_Float16*)alloc(WEL * 2);
    _Float16* Wkt = (_Float16*)alloc(WEL * 2);
    _Float16* Wvt = (_Float16*)alloc(WEL * 2);
    _Float16* Qh  = (_Float16*)alloc(NEL * 2);
    _Float16* Kh  = (_Float16*)alloc(NEL * 2);
    _Float16* Vth = (_Float16*)alloc(NEL * 2);
    _Float16* relh = nullptr;
    if (ws_size >= off + RELE * 2) relh = (_Float16*)alloc(RELE * 2);

    cvt4<<<(int)(NEL / 4 / 256), 256, 0, stream>>>(q, qx, (int)(NEL / 4));
    cvt4<<<(int)(NEL / 4 / 256), 256, 0, stream>>>(k, kx, (int)(NEL / 4));
    cvt4<<<(int)(NEL / 4 / 256), 256, 0, stream>>>(v, vx, (int)(NEL / 4));
    if (relh)
        cvt4<<<(int)(RELE / 4 / 256), 256, 0, stream>>>(rel, relh, (int)(RELE / 4));

    dim3 tg(32, 32);
    wtrans<<<tg, 256, 0, stream>>>(Wq, Wqt);
    wtrans<<<tg, 256, 0, stream>>>(Wk, Wkt);
    wtrans<<<tg, 256, 0, stream>>>(Wv, Wvt);

    dim3 pg(64, 8);
    proj_gemm<<<pg, 256, 0, stream>>>(qx, Wqt, bq, Qh, 1.0f, 0);
    proj_gemm<<<pg, 256, 0, stream>>>(kx, Wkt, bk, Kh, 0.125f, 0); // fold 1/sqrt(dk)
    proj_gemm<<<pg, 256, 0, stream>>>(vx, Wvt, bv, Vth, 1.0f, 1);  // V transposed

    dim3 ag(64, 8);
    attn_kernel<<<ag, 256, 0, stream>>>(Qh, Kh, Vth, relh, rel, mask, out);
}